// Round 4
// baseline (222.621 us; speedup 1.0000x reference)
//
#include <hip/hip_runtime.h>
#include <math.h>

#define N_NODES 8192
#define KNBR    32
#define PDIM    128
#define BINS    64
#define REL_CLIP 32
#define REL_DIM  66

typedef unsigned short ushort_t;
typedef short v8s  __attribute__((ext_vector_type(8)));
typedef short v4s_t __attribute__((ext_vector_type(4)));
typedef float v4f  __attribute__((ext_vector_type(4)));

#define FBS 136   // featB/pairB row stride (ushorts), 272B (16B-mult)
#define HTS 264   // hiddenT row stride (ushorts), 528B
#define LBS 264   // localB row stride (ushorts)

__device__ __forceinline__ ushort_t f2bf(float f) {
    unsigned int u = __float_as_uint(f);
    u += 0x7fffu + ((u >> 16) & 1u);
    return (ushort_t)(u >> 16);
}
// gelu_tanh(x) == x * sigmoid(2*0.7978845608*(x + 0.044715 x^3)) (exact identity)
__device__ __forceinline__ float fast_gelu(float x) {
    float x2 = x * x;
    float y = x * fmaf(x2, 0.07135481627f, 1.5957691216f);
    float e = __expf(-y);
    return x / (1.f + e);
}

// ---------------- Prep: bf16 transposed/combined weights ----------------
// Wcomb[128 col][128 k]: 0..15 dist, 16..18 dir, 19..27 rot, 28..42 pvec,
//                        43..108 relpos one-hot, 109..127 zero
// W1T[256][128], W2T[64][256], W_locT[256][256] (oc<128: W_loc_i, else W_loc_j)
__global__ __launch_bounds__(256) void prep_kernel(
    const float* __restrict__ W_dist, const float* __restrict__ W_dir,
    const float* __restrict__ W_rot, const float* __restrict__ W_pvec,
    const float* __restrict__ W_relpos,
    const float* __restrict__ W1, const float* __restrict__ W2,
    const float* __restrict__ W_loc_i, const float* __restrict__ W_loc_j,
    ushort_t* __restrict__ Wcomb, ushort_t* __restrict__ W1T,
    ushort_t* __restrict__ W2T, ushort_t* __restrict__ W_locT)
{
    int idx = blockIdx.x * 256 + threadIdx.x;
    if (idx < 16384) {
        int col = idx >> 7, k = idx & 127;
        float v = 0.f;
        if (k < 16)       v = W_dist[k * PDIM + col];
        else if (k < 19)  v = W_dir[(k - 16) * PDIM + col];
        else if (k < 28)  v = W_rot[(k - 19) * PDIM + col];
        else if (k < 43)  v = W_pvec[(k - 28) * PDIM + col];
        else if (k < 109) v = W_relpos[(size_t)(k - 43) * PDIM + col];
        Wcomb[idx] = f2bf(v);
    } else if (idx < 49152) {
        int o = idx - 16384;
        int col = o >> 7, k = o & 127;
        W1T[o] = f2bf(W1[(size_t)k * 256 + col]);
    } else if (idx < 65536) {
        int o = idx - 49152;
        int col = o >> 8, k = o & 255;
        W2T[o] = f2bf(W2[(size_t)k * BINS + col]);
    } else if (idx < 131072) {
        int o = idx - 65536;
        int oc = o >> 8, k = o & 255;
        float v = (oc < 128) ? W_loc_i[(size_t)k * 128 + oc]
                             : W_loc_j[(size_t)k * 128 + (oc - 128)];
        W_locT[o] = f2bf(v);
    }
}

// ---------------- locframe: frames + MFMA local projections ----------------
// 256 blocks x 256 thr, 32 nodes/block
__global__ __launch_bounds__(256) void locframe_kernel(
    const float* __restrict__ local, const float* __restrict__ pos,
    const ushort_t* __restrict__ W_locT,
    float* __restrict__ R_ws, float* __restrict__ loci_ws, float* __restrict__ locj_ws)
{
    __shared__ __align__(16) ushort_t LB[32 * LBS];
    const int tid = threadIdx.x;
    const int base = blockIdx.x * 32;
    const int wid = tid >> 6, lane = tid & 63, c15 = lane & 15, hi = lane >> 4;

    if (tid < 32) {  // frames
        const int n = base + tid;
        const float* pp = pos + (size_t)n * 15;
        float nx = pp[0], ny = pp[1], nz = pp[2];
        float cax = pp[3], cay = pp[4], caz = pp[5];
        float cx = pp[6], cy = pp[7], cz = pp[8];
        float e1x = cx - cax, e1y = cy - cay, e1z = cz - caz;
        float n1 = sqrtf(e1x*e1x + e1y*e1y + e1z*e1z) + 1e-8f;
        e1x /= n1; e1y /= n1; e1z /= n1;
        float v2x = nx - cax, v2y = ny - cay, v2z = nz - caz;
        float dp = v2x*e1x + v2y*e1y + v2z*e1z;
        float wx = v2x - dp*e1x, wy = v2y - dp*e1y, wz = v2z - dp*e1z;
        float n2 = sqrtf(wx*wx + wy*wy + wz*wz) + 1e-8f;
        float e2x = wx/n2, e2y = wy/n2, e2z = wz/n2;
        float* R = R_ws + (size_t)n * 9;
        R[0] = e1x; R[1] = e1y; R[2] = e1z;
        R[3] = e2x; R[4] = e2y; R[5] = e2z;
        R[6] = e1y*e2z - e1z*e2y;
        R[7] = e1z*e2x - e1x*e2z;
        R[8] = e1x*e2y - e1y*e2x;
    }
    // stage local -> bf16 LDS
    #pragma unroll
    for (int it = 0; it < 8; ++it) {
        int f = tid + it * 256;          // float4 index, 2048 total
        int row = f >> 6, kc = f & 63;
        float4 L = *(const float4*)&local[((size_t)(base + row)) * 256 + kc * 4];
        v4s_t u;
        u[0] = (short)f2bf(L.x); u[1] = (short)f2bf(L.y);
        u[2] = (short)f2bf(L.z); u[3] = (short)f2bf(L.w);
        *(v4s_t*)&LB[row * LBS + kc * 4] = u;
    }
    __syncthreads();

    v4f acc[4][2];
    #pragma unroll
    for (int a = 0; a < 4; ++a)
        #pragma unroll
        for (int b = 0; b < 2; ++b) { acc[a][b][0]=0.f; acc[a][b][1]=0.f; acc[a][b][2]=0.f; acc[a][b][3]=0.f; }
    #pragma unroll
    for (int ks = 0; ks < 8; ++ks) {
        v8s bF[2];
        #pragma unroll
        for (int bt = 0; bt < 2; ++bt)
            bF[bt] = *(const v8s*)&LB[(bt*16 + c15) * LBS + ks*32 + hi*8];
        #pragma unroll
        for (int act = 0; act < 4; ++act) {
            v8s aF = *(const v8s*)&W_locT[(size_t)(wid*64 + act*16 + c15) * 256 + ks*32 + hi*8];
            #pragma unroll
            for (int bt = 0; bt < 2; ++bt)
                acc[act][bt] = __builtin_amdgcn_mfma_f32_16x16x32_bf16(aF, bF[bt], acc[act][bt], 0, 0, 0);
        }
    }
    #pragma unroll
    for (int act = 0; act < 4; ++act) {
        const int oc0 = wid*64 + act*16 + hi*4;
        #pragma unroll
        for (int bt = 0; bt < 2; ++bt) {
            const int lrow = bt*16 + c15;
            float4 v;
            v.x = acc[act][bt][0]; v.y = acc[act][bt][1];
            v.z = acc[act][bt][2]; v.w = acc[act][bt][3];
            if (oc0 < 128)
                *(float4*)&loci_ws[(size_t)(base + lrow) * 128 + oc0] = v;
            else
                *(float4*)&locj_ws[(size_t)(base + lrow) * 128 + (oc0 - 128)] = v;
        }
    }
}

// ---------------- pair kernel: 4096 blocks x 256 thr, 64 rows (2 nodes) ----------------
__global__ __launch_bounds__(256, 3) void pair_kernel(
    const float* __restrict__ pos, const int* __restrict__ neighbours,
    const int* __restrict__ resi, const int* __restrict__ chain,
    const int* __restrict__ batch, const int* __restrict__ mask,
    const float* __restrict__ ln_scale, const float* __restrict__ ln_bias,
    const float* __restrict__ b1, const float* __restrict__ b2,
    const float* __restrict__ R_ws, const float* __restrict__ loci_ws,
    const float* __restrict__ locj_ws,
    const ushort_t* __restrict__ Wcomb, const ushort_t* __restrict__ W1T,
    const ushort_t* __restrict__ W2T, float* __restrict__ out)
{
    __shared__ __align__(16) ushort_t FB[64 * FBS];   // featB / pairB alias
    __shared__ __align__(16) ushort_t HT[64 * HTS];   // hiddenT
    __shared__ float stage[576];                      // 0:lnsc 128:lnb 256:b1 512:b2

    const int tid = threadIdx.x;
    const int ib = blockIdx.x;
    const int base = ib * 2;
    const int wid = tid >> 6, lane = tid & 63, c15 = lane & 15, hi = lane >> 4;

    if (tid < 144) {
        int t4 = tid * 4;
        float4 v;
        if (tid < 32)       v = *(const float4*)&ln_scale[t4];
        else if (tid < 64)  v = *(const float4*)&ln_bias[t4 - 128];
        else if (tid < 128) v = *(const float4*)&b1[t4 - 256];
        else                v = *(const float4*)&b2[t4 - 512];
        *(float4*)&stage[t4] = v;
    }

    // ---------- P0: per-lane features -> FB (wave-role by chunk class) ----------
    {
        const int row = lane;
        const int node = base + (row >> 5);
        const int nb = neighbours[(size_t)node * KNBR + (row & 31)];
        const int j = nb < 0 ? 0 : nb;
        int rel = resi[j] - resi[node];
        rel = rel < -REL_CLIP ? -REL_CLIP : (rel > REL_CLIP ? REL_CLIP : rel);
        rel += REL_CLIP;
        const int code = ((chain[j] == chain[node]) && (batch[j] == batch[node])) ? rel : (REL_DIM - 1);
        const int sw = row & 7;
        ushort_t* fr = &FB[row * FBS];

        float Ri[9];
        #pragma unroll
        for (int q = 0; q < 9; ++q) Ri[q] = R_ws[(size_t)node * 9 + q];
        const float cax = pos[(size_t)node*15 + 3], cay = pos[(size_t)node*15 + 4], caz = pos[(size_t)node*15 + 5];
        const float* pj = pos + (size_t)j * 15;
        const float dx = pj[3] - cax, dy = pj[4] - cay, dz = pj[5] - caz;

        #define DOTR(b, X, Y, Z) (Ri[(b)*3]*(X) + Ri[(b)*3+1]*(Y) + Ri[(b)*3+2]*(Z))
        #define OHV(v, b0) { _Pragma("unroll") for (int t = 0; t < 8; ++t) (v)[t] = (short)((code == (b0)+t) ? 0x3F80 : 0); }

        if (wid == 0) {
            float d = sqrtf(dx*dx + dy*dy + dz*dz);
            v8s v;
            #pragma unroll
            for (int r = 0; r < 8; ++r) { float dd = d - (22.f/15.f)*r; v[r] = (short)f2bf(__expf(-dd*dd*(1.f/3.78125f))); }
            *(v8s*)&fr[(0 ^ sw) << 3] = v;
            float p2x = pj[6]-cax, p2y = pj[7]-cay, p2z = pj[8]-caz;
            float p3x = pj[9]-cax, p3y = pj[10]-cay, p3z = pj[11]-caz;
            v8s w;
            w[0] = (short)f2bf(DOTR(1, dx, dy, dz));      // q4 (m1,b1)
            w[1] = (short)f2bf(DOTR(2, dx, dy, dz));      // q5
            w[2] = (short)f2bf(DOTR(0, p2x, p2y, p2z));   // q6
            w[3] = (short)f2bf(DOTR(1, p2x, p2y, p2z));
            w[4] = (short)f2bf(DOTR(2, p2x, p2y, p2z));
            w[5] = (short)f2bf(DOTR(0, p3x, p3y, p3z));
            w[6] = (short)f2bf(DOTR(1, p3x, p3y, p3z));
            w[7] = (short)f2bf(DOTR(2, p3x, p3y, p3z));
            *(v8s*)&fr[(4 ^ sw) << 3] = w;
            v8s o1; OHV(o1, 21); *(v8s*)&fr[(8 ^ sw) << 3] = o1;
            v8s o2; OHV(o2, 53); *(v8s*)&fr[(12 ^ sw) << 3] = o2;
        } else if (wid == 1) {
            float d = sqrtf(dx*dx + dy*dy + dz*dz);
            v8s v;
            #pragma unroll
            for (int r = 0; r < 8; ++r) { float dd = d - (22.f/15.f)*(r+8); v[r] = (short)f2bf(__expf(-dd*dd*(1.f/3.78125f))); }
            *(v8s*)&fr[(1 ^ sw) << 3] = v;
            float p4x = pj[12]-cax, p4y = pj[13]-cay, p4z = pj[14]-caz;
            v8s w;
            w[0] = (short)f2bf(DOTR(0, p4x, p4y, p4z));   // q12
            w[1] = (short)f2bf(DOTR(1, p4x, p4y, p4z));
            w[2] = (short)f2bf(DOTR(2, p4x, p4y, p4z));
            #pragma unroll
            for (int t = 3; t < 8; ++t) w[t] = (short)((code == t-3) ? 0x3F80 : 0);   // oh 0..4
            *(v8s*)&fr[(5 ^ sw) << 3] = w;
            v8s o1; OHV(o1, 29); *(v8s*)&fr[(9 ^ sw) << 3] = o1;
            v8s o2; OHV(o2, 61); *(v8s*)&fr[(13 ^ sw) << 3] = o2;
        } else if (wid == 2) {
            float d = sqrtf(dx*dx + dy*dy + dz*dz);
            float inv = 1.f / (d + 1e-8f);
            float ux = dx*inv, uy = dy*inv, uz = dz*inv;
            float Rj[9];
            #pragma unroll
            for (int q = 0; q < 9; ++q) Rj[q] = R_ws[(size_t)j * 9 + q];
            #define ROT(b, c) (Ri[(b)*3]*Rj[(c)*3] + Ri[(b)*3+1]*Rj[(c)*3+1] + Ri[(b)*3+2]*Rj[(c)*3+2])
            v8s v;
            v[0] = (short)f2bf(DOTR(0, ux, uy, uz));
            v[1] = (short)f2bf(DOTR(1, ux, uy, uz));
            v[2] = (short)f2bf(DOTR(2, ux, uy, uz));
            v[3] = (short)f2bf(ROT(0,0));
            v[4] = (short)f2bf(ROT(0,1));
            v[5] = (short)f2bf(ROT(0,2));
            v[6] = (short)f2bf(ROT(1,0));
            v[7] = (short)f2bf(ROT(1,1));
            *(v8s*)&fr[(2 ^ sw) << 3] = v;
            v8s o1; OHV(o1, 5);  *(v8s*)&fr[(6 ^ sw) << 3] = o1;
            v8s o2; OHV(o2, 37); *(v8s*)&fr[(10 ^ sw) << 3] = o2;
            v8s z = {0,0,0,0,0,0,0,0};
            *(v8s*)&fr[(14 ^ sw) << 3] = z;
            #undef ROT
        } else {
            float Rj[9];
            #pragma unroll
            for (int q = 0; q < 9; ++q) Rj[q] = R_ws[(size_t)j * 9 + q];
            #define ROT(b, c) (Ri[(b)*3]*Rj[(c)*3] + Ri[(b)*3+1]*Rj[(c)*3+1] + Ri[(b)*3+2]*Rj[(c)*3+2])
            float p0x = pj[0]-cax, p0y = pj[1]-cay, p0z = pj[2]-caz;
            v8s v;
            v[0] = (short)f2bf(ROT(1,2));
            v[1] = (short)f2bf(ROT(2,0));
            v[2] = (short)f2bf(ROT(2,1));
            v[3] = (short)f2bf(ROT(2,2));
            v[4] = (short)f2bf(DOTR(0, p0x, p0y, p0z));   // q0
            v[5] = (short)f2bf(DOTR(1, p0x, p0y, p0z));
            v[6] = (short)f2bf(DOTR(2, p0x, p0y, p0z));
            v[7] = (short)f2bf(DOTR(0, dx, dy, dz));      // q3 (m1,b0)
            *(v8s*)&fr[(3 ^ sw) << 3] = v;
            v8s o1; OHV(o1, 13); *(v8s*)&fr[(7 ^ sw) << 3] = o1;
            v8s o2; OHV(o2, 45); *(v8s*)&fr[(11 ^ sw) << 3] = o2;
            v8s z = {0,0,0,0,0,0,0,0};
            *(v8s*)&fr[(15 ^ sw) << 3] = z;
            #undef ROT
        }
        #undef DOTR
        #undef OHV
    }
    __syncthreads();   // bar0

    // ---------- P1: pairT GEMM C[pcol][prow] = Wcomb x featB, +init, LN in-reg ----------
    {
        const int prow = wid * 16 + c15;
        const int sw = c15 & 7;
        v4f acc[8];
        #pragma unroll
        for (int a = 0; a < 8; ++a) { acc[a][0]=0.f; acc[a][1]=0.f; acc[a][2]=0.f; acc[a][3]=0.f; }
        #pragma unroll
        for (int ks = 0; ks < 4; ++ks) {
            v8s bF = *(const v8s*)&FB[prow * FBS + (((ks*4 + hi) ^ sw) << 3)];
            #pragma unroll
            for (int at = 0; at < 8; ++at) {
                v8s aF = *(const v8s*)&Wcomb[(size_t)(at*16 + c15) * 128 + ks*32 + hi*8];
                acc[at] = __builtin_amdgcn_mfma_f32_16x16x32_bf16(aF, bF, acc[at], 0, 0, 0);
            }
        }
        const int node = base + (prow >> 5);
        const int nb = neighbours[(size_t)node * KNBR + (prow & 31)];
        const int j = nb < 0 ? 0 : nb;
        const float pm = (mask[node] != 0 && mask[j] != 0 && nb != -1) ? 1.f : 0.f;
        float s = 0.f, sq = 0.f;
        #pragma unroll
        for (int at = 0; at < 8; ++at) {
            const int col0 = at*16 + hi*4;
            float4 li = *(const float4*)&loci_ws[(size_t)node * 128 + col0];
            float4 lj = *(const float4*)&locj_ws[(size_t)j * 128 + col0];
            float v0 = (acc[at][0] + li.x + lj.x) * pm;
            float v1 = (acc[at][1] + li.y + lj.y) * pm;
            float v2 = (acc[at][2] + li.z + lj.z) * pm;
            float v3 = (acc[at][3] + li.w + lj.w) * pm;
            acc[at][0] = v0; acc[at][1] = v1; acc[at][2] = v2; acc[at][3] = v3;
            s += v0 + v1 + v2 + v3;
            sq += v0*v0 + v1*v1 + v2*v2 + v3*v3;
        }
        s  += __shfl_xor(s, 16, 64);  sq += __shfl_xor(sq, 16, 64);
        s  += __shfl_xor(s, 32, 64);  sq += __shfl_xor(sq, 32, 64);
        const float mu = s * (1.f/128.f);
        const float rstd = rsqrtf(sq * (1.f/128.f) - mu*mu + 1e-5f);
        const float nm = -mu * rstd;
        #pragma unroll
        for (int at = 0; at < 8; ++at) {
            const int col0 = at*16 + hi*4;
            float4 sc = *(const float4*)&stage[col0];
            float4 bb = *(const float4*)&stage[128 + col0];
            v4s_t u;
            u[0] = (short)f2bf(fmaf(fmaf(acc[at][0], rstd, nm), sc.x, bb.x));
            u[1] = (short)f2bf(fmaf(fmaf(acc[at][1], rstd, nm), sc.y, bb.y));
            u[2] = (short)f2bf(fmaf(fmaf(acc[at][2], rstd, nm), sc.z, bb.z));
            u[3] = (short)f2bf(fmaf(fmaf(acc[at][3], rstd, nm), sc.w, bb.w));
            const int chunkW = (col0 >> 3) ^ sw;
            *(v4s_t*)&FB[prow * FBS + (chunkW << 3) + (hi & 1) * 4] = u;
        }
    }
    __syncthreads();   // bar1

    // ---------- P4: hiddenT GEMM C[h][prow] = W1T x pairB, gelu, -> HT ----------
    {
        const int sw = c15 & 7;
        v4f acc[4][4];
        #pragma unroll
        for (int a = 0; a < 4; ++a)
            #pragma unroll
            for (int b = 0; b < 4; ++b) { acc[a][b][0]=0.f; acc[a][b][1]=0.f; acc[a][b][2]=0.f; acc[a][b][3]=0.f; }
        #pragma unroll
        for (int ks = 0; ks < 4; ++ks) {
            v8s bF[4];
            #pragma unroll
            for (int bt = 0; bt < 4; ++bt)
                bF[bt] = *(const v8s*)&FB[(bt*16 + c15) * FBS + (((ks*4 + hi) ^ sw) << 3)];
            #pragma unroll
            for (int ht = 0; ht < 4; ++ht) {
                v8s aF = *(const v8s*)&W1T[(size_t)(wid*64 + ht*16 + c15) * 128 + ks*32 + hi*8];
                #pragma unroll
                for (int bt = 0; bt < 4; ++bt)
                    acc[ht][bt] = __builtin_amdgcn_mfma_f32_16x16x32_bf16(aF, bF[bt], acc[ht][bt], 0, 0, 0);
            }
        }
        #pragma unroll
        for (int ht = 0; ht < 4; ++ht) {
            const int h0 = wid*64 + ht*16 + hi*4;
            float4 bv = *(const float4*)&stage[256 + h0];
            #pragma unroll
            for (int bt = 0; bt < 4; ++bt) {
                v4s_t u;
                u[0] = (short)f2bf(fast_gelu(acc[ht][bt][0] + bv.x));
                u[1] = (short)f2bf(fast_gelu(acc[ht][bt][1] + bv.y));
                u[2] = (short)f2bf(fast_gelu(acc[ht][bt][2] + bv.z));
                u[3] = (short)f2bf(fast_gelu(acc[ht][bt][3] + bv.w));
                *(v4s_t*)&HT[(bt*16 + c15) * HTS + h0] = u;
            }
        }
    }
    __syncthreads();   // bar2

    // ---------- P5: logits = hidden @ W2 + softmax in-reg -> out ----------
    {
        v4f acc[4];
        #pragma unroll
        for (int a = 0; a < 4; ++a) { acc[a][0]=0.f; acc[a][1]=0.f; acc[a][2]=0.f; acc[a][3]=0.f; }
        #pragma unroll
        for (int ks = 0; ks < 8; ++ks) {
            v8s aF = *(const v8s*)&HT[(wid*16 + c15) * HTS + ks*32 + hi*8];
            #pragma unroll
            for (int ct = 0; ct < 4; ++ct) {
                v8s bF = *(const v8s*)&W2T[(size_t)(ct*16 + c15) * 256 + ks*32 + hi*8];
                acc[ct] = __builtin_amdgcn_mfma_f32_16x16x32_bf16(aF, bF, acc[ct], 0, 0, 0);
            }
        }
        float bv0 = stage[512 + c15];
        float bv1 = stage[512 + 16 + c15];
        float bv2 = stage[512 + 32 + c15];
        float bv3 = stage[512 + 48 + c15];
        #pragma unroll
        for (int r = 0; r < 4; ++r) {
            float v0 = acc[0][r] + bv0;
            float v1 = acc[1][r] + bv1;
            float v2 = acc[2][r] + bv2;
            float v3 = acc[3][r] + bv3;
            float m = fmaxf(fmaxf(v0, v1), fmaxf(v2, v3));
            m = fmaxf(m, __shfl_xor(m, 1, 64));
            m = fmaxf(m, __shfl_xor(m, 2, 64));
            m = fmaxf(m, __shfl_xor(m, 4, 64));
            m = fmaxf(m, __shfl_xor(m, 8, 64));
            float S = __expf(v0 - m) + __expf(v1 - m) + __expf(v2 - m) + __expf(v3 - m);
            S += __shfl_xor(S, 1, 64);
            S += __shfl_xor(S, 2, 64);
            S += __shfl_xor(S, 4, 64);
            S += __shfl_xor(S, 8, 64);
            const float lz = m + __logf(S);
            const size_t ob = ((size_t)(ib * 64 + wid*16 + hi*4 + r)) * 64;
            out[ob + c15]      = v0 - lz;
            out[ob + 16 + c15] = v1 - lz;
            out[ob + 32 + c15] = v2 - lz;
            out[ob + 48 + c15] = v3 - lz;
        }
    }
}

extern "C" void kernel_launch(void* const* d_in, const int* in_sizes, int n_in,
                              void* d_out, int out_size, void* d_ws, size_t ws_size,
                              hipStream_t stream) {
    (void)in_sizes; (void)n_in; (void)out_size; (void)ws_size;
    const float* local   = (const float*)d_in[0];
    const float* pos     = (const float*)d_in[1];
    const int* neighbours= (const int*)d_in[2];
    const int* resi      = (const int*)d_in[3];
    const int* chain     = (const int*)d_in[4];
    const int* batch     = (const int*)d_in[5];
    const int* mask      = (const int*)d_in[6];
    const float* W_relpos= (const float*)d_in[7];
    const float* W_dist  = (const float*)d_in[8];
    const float* W_dir   = (const float*)d_in[9];
    const float* W_rot   = (const float*)d_in[10];
    const float* W_pvec  = (const float*)d_in[11];
    const float* W_loc_i = (const float*)d_in[12];
    const float* W_loc_j = (const float*)d_in[13];
    const float* ln_scale= (const float*)d_in[14];
    const float* ln_bias = (const float*)d_in[15];
    const float* W1      = (const float*)d_in[16];
    const float* b1      = (const float*)d_in[17];
    const float* W2      = (const float*)d_in[18];
    const float* b2      = (const float*)d_in[19];
    float* out = (float*)d_out;

    float* R_ws    = (float*)d_ws;                          // 8192*9
    float* loci_ws = R_ws + (size_t)N_NODES * 9;            // 8192*128
    float* locj_ws = loci_ws + (size_t)N_NODES * PDIM;      // 8192*128
    ushort_t* Wcomb = (ushort_t*)(locj_ws + (size_t)N_NODES * PDIM);
    ushort_t* W1T   = Wcomb + 128 * 128;
    ushort_t* W2T   = W1T + 256 * 128;
    ushort_t* W_locT= W2T + 64 * 256;                       // 256*256

    hipLaunchKernelGGL(prep_kernel, dim3(512), dim3(256), 0, stream,
                       W_dist, W_dir, W_rot, W_pvec, W_relpos, W1, W2,
                       W_loc_i, W_loc_j, Wcomb, W1T, W2T, W_locT);
    hipLaunchKernelGGL(locframe_kernel, dim3(N_NODES / 32), dim3(256), 0, stream,
                       local, pos, W_locT, R_ws, loci_ws, locj_ws);
    hipLaunchKernelGGL(pair_kernel, dim3(N_NODES / 2), dim3(256), 0, stream,
                       pos, neighbours, resi, chain, batch, mask,
                       ln_scale, ln_bias, b1, b2,
                       R_ws, loci_ws, locj_ws, Wcomb, W1T, W2T, out);
}